// Round 1
// baseline (767.642 us; speedup 1.0000x reference)
//
#include <hip/hip_runtime.h>
#include <math.h>

typedef unsigned int u32;
typedef unsigned long long u64;

#define NANCH   36864
#define PRE     6000
#define POST    2000
#define NWORDS  94        // ceil(6000/64)

// ---------------- workspace layout (bytes) ----------------
#define OFF_PROPS   ((size_t)0)                    // 36864 * 16 = 589824
#define OFF_SV      ((size_t)589824)               // 36864 * 8  = 294912
#define OFF_TOPBOX  ((size_t)884736)               // 6016 * 16  = 96256
#define OFF_SORTED  ((size_t)980992)               // 6016 * 8   = 48128
#define OFF_SEL     ((size_t)1029120)              // 6016 * 8   = 48128
#define OFF_TOPKEY  ((size_t)1077248)              // 6016 * 4   = 24064
#define OFF_INVALW  ((size_t)1101312)              // 94 * 8 -> pad 768
#define OFF_MASK    ((size_t)1102080)              // 6000 * 94 * 8 = 4512000
#define OFF_ZERO    ((size_t)5614080)              // zeroed region start
#define OFF_H1      (OFF_ZERO)                     // 65536 * 4
#define OFF_H2      (OFF_H1 + 262144)
#define OFF_H3      (OFF_H2 + 262144)
#define OFF_CTRL    (OFF_H3 + 262144)              // 256 B: u32[0..7] + u64 T at +32
#define OFF_KEEPW   (OFF_CTRL + 256)               // 94*8 -> pad 768
#define ZERO_BYTES  ((size_t)(262144*3 + 256 + 768))

// base anchors for base_size=16, ratios(0.5,1,2), scales(8,16,32) — np.round (banker's) applied
__device__ __constant__ float BA[9][4] = {
  {-84.f,-40.f,99.f,55.f},   {-176.f,-88.f,191.f,103.f}, {-360.f,-184.f,375.f,199.f},
  {-56.f,-56.f,71.f,71.f},   {-120.f,-120.f,135.f,135.f},{-248.f,-248.f,263.f,263.f},
  {-36.f,-80.f,51.f,95.f},   {-80.f,-168.f,95.f,183.f},  {-168.f,-344.f,183.f,359.f}};

// ---------------- 1) decode ----------------
__global__ void decode_k(const float* __restrict__ deltas, const float* __restrict__ scores,
                         const int* __restrict__ imw_p, const int* __restrict__ imh_p,
                         float4* __restrict__ props, u64* __restrict__ sortvals) {
  #pragma clang fp contract(off)
  int i = blockIdx.x * 256 + threadIdx.x;
  if (i >= NANCH) return;
  int a = i % 9;
  int pix = i / 9;
  int x = pix & 63, y = pix >> 6;

  float sc = scores[(9 + a) * 4096 + pix];
  float d0 = deltas[(a * 4 + 0) * 4096 + pix];
  float d1 = deltas[(a * 4 + 1) * 4096 + pix];
  float d2 = deltas[(a * 4 + 2) * 4096 + pix];
  float d3 = deltas[(a * 4 + 3) * 4096 + pix];

  float gx = (float)(x * 16), gy = (float)(y * 16);
  float ax1 = gx + BA[a][0], ay1 = gy + BA[a][1];
  float ax2 = gx + BA[a][2], ay2 = gy + BA[a][3];
  float aw = ax2 - ax1 + 1.0f, ah = ay2 - ay1 + 1.0f;
  float acx = ax1 + 0.5f * aw, acy = ay1 + 0.5f * ah;

  float pcx = d0 * aw + acx;
  float pcy = d1 * ah + acy;
  float pw = (float)exp((double)d2) * aw;   // f64 exp -> correctly-rounded f32
  float ph = (float)exp((double)d3) * ah;

  float imw1 = (float)imw_p[0] - 1.0f, imh1 = (float)imh_p[0] - 1.0f;
  float x1 = fminf(fmaxf(pcx - 0.5f * pw, 0.0f), imw1);
  float y1 = fminf(fmaxf(pcy - 0.5f * ph, 0.0f), imh1);
  float x2 = fminf(fmaxf(pcx + 0.5f * pw, 0.0f), imw1);
  float y2 = fminf(fmaxf(pcy + 0.5f * ph, 0.0f), imh1);
  props[i] = make_float4(x1, y1, x2, y2);

  float thresh = 16.0f * ((float)imh_p[0] / (float)imw_p[0]);
  bool keep = (x2 - x1 + 1.0f >= thresh) && (y2 - y1 + 1.0f >= thresh);
  u32 key = keep ? (__float_as_uint(sc) | 0x80000000u) : 0u;  // scores >= 0
  sortvals[i] = ((u64)key << 32) | (u64)(0xFFFFFFFFu - (u32)i); // distinct; desc order == top_k order
}

// ---------------- 2) exact top-6000 threshold via 3-level radix histogram ----------------
__global__ void hist_k(const u64* __restrict__ sv, u32* __restrict__ hist,
                       const u32* __restrict__ ctrl, int level) {
  int i = blockIdx.x * 256 + threadIdx.x;
  if (i >= NANCH) return;
  u64 v = sv[i];
  if (level == 1) {
    atomicAdd(&hist[(u32)(v >> 48)], 1u);
  } else if (level == 2) {
    if ((u32)(v >> 48) == ctrl[0]) atomicAdd(&hist[(u32)(v >> 32) & 0xFFFFu], 1u);
  } else {
    u32 pfx = (ctrl[0] << 16) | ctrl[2];
    if ((u32)(v >> 32) == pfx) atomicAdd(&hist[(u32)v & 0xFFFFu], 1u);
  }
}

__global__ void scan_k(const u32* __restrict__ hist, u32* __restrict__ ctrl, int level) {
  __shared__ u32 part[1024];
  int t = threadIdx.x;
  u32 ssum = 0;
  for (int b = 0; b < 64; ++b) ssum += hist[t * 64 + b];
  part[t] = ssum;
  __syncthreads();
  if (t == 0) {
    u32 Rin = (level == 1) ? (u32)PRE : ctrl[(level - 1) * 2 - 1];
    u32 acc = 0; int pt;
    for (pt = 1023; pt >= 0; --pt) {
      if (acc + part[pt] >= Rin) break;
      acc += part[pt];
    }
    int chosen = pt * 64; u32 Rout = Rin;
    for (int b = pt * 64 + 63; b >= pt * 64; --b) {
      u32 h = hist[b];
      if (acc + h >= Rin) { chosen = b; Rout = Rin - acc; break; }
      acc += h;
    }
    ctrl[(level - 1) * 2] = (u32)chosen;
    ctrl[(level - 1) * 2 + 1] = Rout;
    if (level == 3) {
      // bits 16..31 of every sortval are 0xFFFF (idx < 65536)
      u64 T = ((u64)ctrl[0] << 48) | ((u64)ctrl[2] << 32) | 0xFFFF0000ULL | (u64)(u32)chosen;
      *(u64*)(&ctrl[8]) = T;   // exactly 6000 sortvals are >= T (all distinct)
    }
  }
}

__global__ void compact_k(const u64* __restrict__ sv, u32* __restrict__ ctrl,
                          u64* __restrict__ sel) {
  int i = blockIdx.x * 256 + threadIdx.x;
  if (i >= NANCH) return;
  u64 T = *(const u64*)(&ctrl[8]);
  u64 v = sv[i];
  if (v >= T) {
    u32 p = atomicAdd(&ctrl[6], 1u);
    sel[p] = v;
  }
}

// ---------------- 3) single-block bitonic sort of the 6000 selected (desc) ----------------
__global__ void sort_k(const u64* __restrict__ sel, u64* __restrict__ sorted) {
  __shared__ u64 s[8192];   // 64 KiB
  int tid = threadIdx.x;
  for (int idx = tid; idx < 8192; idx += 1024)
    s[idx] = (idx < PRE) ? ~sel[idx] : ~0ULL;   // ascending sort of complement == descending original
  __syncthreads();
  for (int k = 2; k <= 8192; k <<= 1) {
    for (int j = k >> 1; j > 0; j >>= 1) {
      for (int t = tid; t < 8192; t += 1024) {
        int ixj = t ^ j;
        if (ixj > t) {
          u64 A = s[t], B = s[ixj];
          bool asc = ((t & k) == 0);
          if (asc ? (A > B) : (A < B)) { s[t] = B; s[ixj] = A; }
        }
      }
      __syncthreads();
    }
  }
  for (int idx = tid; idx < PRE; idx += 1024) sorted[idx] = ~s[idx];
}

// ---------------- 4) gather boxes/keys; build invalid-bit words ----------------
__global__ void gather_k(const u64* __restrict__ sorted, const float4* __restrict__ props,
                         float4* __restrict__ topbox, u32* __restrict__ topkey,
                         u64* __restrict__ invalw) {
  int r = blockIdx.x * 64 + threadIdx.x;
  u32 key = 0;
  if (r < PRE) {
    u64 v = sorted[r];
    key = (u32)(v >> 32);
    u32 idx = 0xFFFFu - ((u32)v & 0xFFFFu);
    topbox[r] = props[idx];
    topkey[r] = key;
  }
  u64 inval = __ballot(key == 0u);
  if (threadIdx.x == 0) invalw[blockIdx.x] = inval;
}

// ---------------- 5) suppression bitmask: 94x94 tiles of 64x64 IoUs ----------------
__global__ void mask_k(const float4* __restrict__ topbox, u64* __restrict__ mask) {
  #pragma clang fp contract(off)
  __shared__ float4 cb[64];
  int jb = blockIdx.x;
  int i = blockIdx.y * 64 + threadIdx.x;
  int jj = jb * 64 + threadIdx.x;
  cb[threadIdx.x] = (jj < PRE) ? topbox[jj] : make_float4(0.f, 0.f, 0.f, 0.f);
  __syncthreads();
  if (i >= PRE) return;
  float4 b = topbox[i];
  float ai = (b.z - b.x + 1.0f) * (b.w - b.y + 1.0f);
  u64 bits = 0ULL;
  int jmax = min(64, PRE - jb * 64);
  for (int j = 0; j < jmax; ++j) {
    float4 c = cb[j];
    float aj = (c.z - c.x + 1.0f) * (c.w - c.y + 1.0f);
    float iw = fmaxf(fminf(b.z, c.z) - fmaxf(b.x, c.x) + 1.0f, 0.0f);
    float ih = fmaxf(fminf(b.w, c.w) - fmaxf(b.y, c.y) + 1.0f, 0.0f);
    float inter = iw * ih;
    float iou = inter / (ai + aj - inter);
    bits |= ((u64)(iou > 0.7f)) << j;
  }
  mask[(size_t)i * NWORDS + jb] = bits;
}

// ---------------- 6) sequential greedy scan: single wave, remv in registers ----------------
__global__ void nms_scan_k(const u64* __restrict__ mask, const u64* __restrict__ invalw,
                           u64* __restrict__ keepw) {
  int lane = threadIdx.x;                       // 64 lanes
  u64 remv0 = invalw[lane];                     // word `lane`
  u64 remv1 = (lane < 30) ? invalw[64 + lane] : 0ULL;  // word `64+lane`
  u64 a0[8], a1[8], b0[8], b1[8];
  int kept = 0; u64 kw = 0ULL;

#define LOADC(cc, B0, B1) { \
    size_t base = (size_t)(cc) * 8 * NWORDS; \
    _Pragma("unroll") \
    for (int k = 0; k < 8; ++k) { \
      B0[k] = mask[base + (size_t)k * NWORDS + lane]; \
      B1[k] = (lane < 30) ? mask[base + (size_t)k * NWORDS + 64 + lane] : 0ULL; \
    } }

#define PROCC(cc, B0, B1) { \
    _Pragma("unroll") \
    for (int k = 0; k < 8; ++k) { \
      int i = (cc) * 8 + k; \
      int w = i >> 6; \
      u64 word = (w < 64) ? __shfl(remv0, w) : __shfl(remv1, w - 64); \
      int keep = (int)((~(word >> (i & 63))) & 1ULL); \
      u64 m = keep ? ~0ULL : 0ULL; \
      remv0 |= B0[k] & m; \
      remv1 |= B1[k] & m; \
      kw |= ((u64)(u32)keep) << (i & 63); \
      kept += keep; \
    } \
    if (lane == 0) keepw[(((cc) * 8) + 7) >> 6] = kw; \
    if (((cc) & 7) == 7) kw = 0ULL; \
    if (kept >= POST) return; }

  LOADC(0, a0, a1);
  for (int c = 0; c < 750; c += 2) {
    if (c + 1 < 750) LOADC(c + 1, b0, b1);
    PROCC(c, a0, a1);
    if (c + 1 >= 750) break;
    if (c + 2 < 750) LOADC(c + 2, a0, a1);
    PROCC(c + 1, b0, b1);
  }
#undef LOADC
#undef PROCC
}

// ---------------- 7) rank + scatter outputs ----------------
__global__ void scatter_k(const u64* __restrict__ keepw, const float4* __restrict__ topbox,
                          const u32* __restrict__ topkey, float* __restrict__ out) {
  __shared__ u64 wl[NWORDS];
  __shared__ u32 pre[NWORDS];
  int t = threadIdx.x;
  if (t < NWORDS) wl[t] = keepw[t];
  __syncthreads();
  if (t == 0) {
    u32 run = 0;
    for (int w = 0; w < NWORDS; ++w) { pre[w] = run; run += (u32)__popcll(wl[w]); }
  }
  __syncthreads();
  for (int i = t; i < PRE; i += 1024) {
    int w = i >> 6;
    u64 word = wl[w];
    if ((word >> (i & 63)) & 1ULL) {
      u32 rank = pre[w] + (u32)__popcll(word & ((1ULL << (i & 63)) - 1ULL));
      if (rank < POST) {
        float4 b = topbox[i];
        out[rank * 5 + 1] = b.x;
        out[rank * 5 + 2] = b.y;
        out[rank * 5 + 3] = b.z;
        out[rank * 5 + 4] = b.w;
        out[10000 + rank] = __uint_as_float(topkey[i] & 0x7FFFFFFFu);  // col 0 stays 0
      }
    }
  }
}

extern "C" void kernel_launch(void* const* d_in, const int* in_sizes, int n_in,
                              void* d_out, int out_size, void* d_ws, size_t ws_size,
                              hipStream_t stream) {
  const float* deltas = (const float*)d_in[0];
  const float* scores = (const float*)d_in[1];
  const int* imw = (const int*)d_in[2];
  const int* imh = (const int*)d_in[3];
  char* ws = (char*)d_ws;

  float4* props   = (float4*)(ws + OFF_PROPS);
  u64*    svals   = (u64*)(ws + OFF_SV);
  float4* topbox  = (float4*)(ws + OFF_TOPBOX);
  u64*    sorted  = (u64*)(ws + OFF_SORTED);
  u64*    sel     = (u64*)(ws + OFF_SEL);
  u32*    topkey  = (u32*)(ws + OFF_TOPKEY);
  u64*    invalw  = (u64*)(ws + OFF_INVALW);
  u64*    maskb   = (u64*)(ws + OFF_MASK);
  u32*    h1      = (u32*)(ws + OFF_H1);
  u32*    h2      = (u32*)(ws + OFF_H2);
  u32*    h3      = (u32*)(ws + OFF_H3);
  u32*    ctrl    = (u32*)(ws + OFF_CTRL);
  u64*    keepw   = (u64*)(ws + OFF_KEEPW);

  hipMemsetAsync(ws + OFF_ZERO, 0, ZERO_BYTES, stream);      // hists + ctrl + keepwords
  hipMemsetAsync(d_out, 0, 12000 * sizeof(float), stream);   // blob + scores zero-padded

  decode_k<<<144, 256, 0, stream>>>(deltas, scores, imw, imh, props, svals);

  hist_k<<<144, 256, 0, stream>>>(svals, h1, ctrl, 1);
  scan_k<<<1, 1024, 0, stream>>>(h1, ctrl, 1);
  hist_k<<<144, 256, 0, stream>>>(svals, h2, ctrl, 2);
  scan_k<<<1, 1024, 0, stream>>>(h2, ctrl, 2);
  hist_k<<<144, 256, 0, stream>>>(svals, h3, ctrl, 3);
  scan_k<<<1, 1024, 0, stream>>>(h3, ctrl, 3);

  compact_k<<<144, 256, 0, stream>>>(svals, ctrl, sel);
  sort_k<<<1, 1024, 0, stream>>>(sel, sorted);
  gather_k<<<94, 64, 0, stream>>>(sorted, props, topbox, topkey, invalw);

  dim3 mgrid(NWORDS, NWORDS);
  mask_k<<<mgrid, 64, 0, stream>>>(topbox, maskb);

  nms_scan_k<<<1, 64, 0, stream>>>(maskb, invalw, keepw);
  scatter_k<<<1, 1024, 0, stream>>>(keepw, topbox, topkey, (float*)d_out);
}

// Round 2
// 746.607 us; speedup vs baseline: 1.0282x; 1.0282x over previous
//
#include <hip/hip_runtime.h>
#include <math.h>

typedef unsigned int u32;
typedef unsigned long long u64;

#define NANCH   36864
#define PRE     6000
#define POST    2000
#define NWORDS  94        // ceil(6000/64)

// ---------------- workspace layout (bytes) ----------------
#define OFF_PROPS   ((size_t)0)                    // 36864 * 16 = 589824
#define OFF_SV      ((size_t)589824)               // 36864 * 8  = 294912
#define OFF_TOPBOX  ((size_t)884736)               // 6016 * 16  = 96256
#define OFF_SORTED  ((size_t)980992)               // 6016 * 8   = 48128
#define OFF_SEL     ((size_t)1029120)              // 6016 * 8   = 48128
#define OFF_TOPKEY  ((size_t)1077248)              // 6016 * 4   = 24064
#define OFF_INVALW  ((size_t)1101312)              // 94 * 8 -> pad 768 (16B aligned)
#define OFF_MASK    ((size_t)1102080)              // 6000 * 94 * 8 = 4512000 (16B aligned)
#define OFF_ZERO    ((size_t)5614080)              // zeroed region start
#define OFF_H1      (OFF_ZERO)                     // 65536 * 4
#define OFF_H2      (OFF_H1 + 262144)
#define OFF_H3      (OFF_H2 + 262144)
#define OFF_CTRL    (OFF_H3 + 262144)              // 256 B: u32[0..7] + u64 T at +32
#define OFF_KEEPW   (OFF_CTRL + 256)               // 94*8 -> pad 768
#define ZERO_BYTES  ((size_t)(262144*3 + 256 + 768))

struct __align__(16) u64x2 { u64 x, y; };

// base anchors for base_size=16, ratios(0.5,1,2), scales(8,16,32) — np.round (banker's) applied
__device__ __constant__ float BA[9][4] = {
  {-84.f,-40.f,99.f,55.f},   {-176.f,-88.f,191.f,103.f}, {-360.f,-184.f,375.f,199.f},
  {-56.f,-56.f,71.f,71.f},   {-120.f,-120.f,135.f,135.f},{-248.f,-248.f,263.f,263.f},
  {-36.f,-80.f,51.f,95.f},   {-80.f,-168.f,95.f,183.f},  {-168.f,-344.f,183.f,359.f}};

// ---------------- 1) decode ----------------
__global__ void decode_k(const float* __restrict__ deltas, const float* __restrict__ scores,
                         const int* __restrict__ imw_p, const int* __restrict__ imh_p,
                         float4* __restrict__ props, u64* __restrict__ sortvals) {
  #pragma clang fp contract(off)
  int i = blockIdx.x * 256 + threadIdx.x;
  if (i >= NANCH) return;
  int a = i % 9;
  int pix = i / 9;
  int x = pix & 63, y = pix >> 6;

  float sc = scores[(9 + a) * 4096 + pix];
  float d0 = deltas[(a * 4 + 0) * 4096 + pix];
  float d1 = deltas[(a * 4 + 1) * 4096 + pix];
  float d2 = deltas[(a * 4 + 2) * 4096 + pix];
  float d3 = deltas[(a * 4 + 3) * 4096 + pix];

  float gx = (float)(x * 16), gy = (float)(y * 16);
  float ax1 = gx + BA[a][0], ay1 = gy + BA[a][1];
  float ax2 = gx + BA[a][2], ay2 = gy + BA[a][3];
  float aw = ax2 - ax1 + 1.0f, ah = ay2 - ay1 + 1.0f;
  float acx = ax1 + 0.5f * aw, acy = ay1 + 0.5f * ah;

  float pcx = d0 * aw + acx;
  float pcy = d1 * ah + acy;
  float pw = (float)exp((double)d2) * aw;   // f64 exp -> correctly-rounded f32
  float ph = (float)exp((double)d3) * ah;

  float imw1 = (float)imw_p[0] - 1.0f, imh1 = (float)imh_p[0] - 1.0f;
  float x1 = fminf(fmaxf(pcx - 0.5f * pw, 0.0f), imw1);
  float y1 = fminf(fmaxf(pcy - 0.5f * ph, 0.0f), imh1);
  float x2 = fminf(fmaxf(pcx + 0.5f * pw, 0.0f), imw1);
  float y2 = fminf(fmaxf(pcy + 0.5f * ph, 0.0f), imh1);
  props[i] = make_float4(x1, y1, x2, y2);

  float thresh = 16.0f * ((float)imh_p[0] / (float)imw_p[0]);
  bool keep = (x2 - x1 + 1.0f >= thresh) && (y2 - y1 + 1.0f >= thresh);
  u32 key = keep ? (__float_as_uint(sc) | 0x80000000u) : 0u;  // scores >= 0
  sortvals[i] = ((u64)key << 32) | (u64)(0xFFFFFFFFu - (u32)i); // distinct; desc order == top_k order
}

// ---------------- 2) exact top-6000 threshold via 3-level radix histogram ----------------
__global__ void hist_k(const u64* __restrict__ sv, u32* __restrict__ hist,
                       const u32* __restrict__ ctrl, int level) {
  int i = blockIdx.x * 256 + threadIdx.x;
  if (i >= NANCH) return;
  u64 v = sv[i];
  if (level == 1) {
    atomicAdd(&hist[(u32)(v >> 48)], 1u);
  } else if (level == 2) {
    if ((u32)(v >> 48) == ctrl[0]) atomicAdd(&hist[(u32)(v >> 32) & 0xFFFFu], 1u);
  } else {
    u32 pfx = (ctrl[0] << 16) | ctrl[2];
    if ((u32)(v >> 32) == pfx) atomicAdd(&hist[(u32)v & 0xFFFFu], 1u);
  }
}

__global__ void scan_k(const u32* __restrict__ hist, u32* __restrict__ ctrl, int level) {
  __shared__ u32 part[1024];
  int t = threadIdx.x;
  u32 ssum = 0;
  for (int b = 0; b < 64; ++b) ssum += hist[t * 64 + b];
  part[t] = ssum;
  __syncthreads();
  if (t == 0) {
    u32 Rin = (level == 1) ? (u32)PRE : ctrl[(level - 1) * 2 - 1];
    u32 acc = 0; int pt;
    for (pt = 1023; pt >= 0; --pt) {
      if (acc + part[pt] >= Rin) break;
      acc += part[pt];
    }
    int chosen = pt * 64; u32 Rout = Rin;
    for (int b = pt * 64 + 63; b >= pt * 64; --b) {
      u32 h = hist[b];
      if (acc + h >= Rin) { chosen = b; Rout = Rin - acc; break; }
      acc += h;
    }
    ctrl[(level - 1) * 2] = (u32)chosen;
    ctrl[(level - 1) * 2 + 1] = Rout;
    if (level == 3) {
      // bits 16..31 of every sortval are 0xFFFF (idx < 65536)
      u64 T = ((u64)ctrl[0] << 48) | ((u64)ctrl[2] << 32) | 0xFFFF0000ULL | (u64)(u32)chosen;
      *(u64*)(&ctrl[8]) = T;   // exactly 6000 sortvals are >= T (all distinct)
    }
  }
}

__global__ void compact_k(const u64* __restrict__ sv, u32* __restrict__ ctrl,
                          u64* __restrict__ sel) {
  int i = blockIdx.x * 256 + threadIdx.x;
  if (i >= NANCH) return;
  u64 T = *(const u64*)(&ctrl[8]);
  u64 v = sv[i];
  if (v >= T) {
    u32 p = atomicAdd(&ctrl[6], 1u);
    sel[p] = v;
  }
}

// ---------------- 3) single-block bitonic sort of the 6000 selected (desc) ----------------
__global__ void sort_k(const u64* __restrict__ sel, u64* __restrict__ sorted) {
  __shared__ u64 s[8192];   // 64 KiB
  int tid = threadIdx.x;
  for (int idx = tid; idx < 8192; idx += 1024)
    s[idx] = (idx < PRE) ? ~sel[idx] : ~0ULL;   // ascending sort of complement == descending original
  __syncthreads();
  for (int k = 2; k <= 8192; k <<= 1) {
    for (int j = k >> 1; j > 0; j >>= 1) {
      for (int t = tid; t < 8192; t += 1024) {
        int ixj = t ^ j;
        if (ixj > t) {
          u64 A = s[t], B = s[ixj];
          bool asc = ((t & k) == 0);
          if (asc ? (A > B) : (A < B)) { s[t] = B; s[ixj] = A; }
        }
      }
      __syncthreads();
    }
  }
  for (int idx = tid; idx < PRE; idx += 1024) sorted[idx] = ~s[idx];
}

// ---------------- 4) gather boxes/keys; build invalid-bit words ----------------
__global__ void gather_k(const u64* __restrict__ sorted, const float4* __restrict__ props,
                         float4* __restrict__ topbox, u32* __restrict__ topkey,
                         u64* __restrict__ invalw) {
  int r = blockIdx.x * 64 + threadIdx.x;
  u32 key = 0;
  if (r < PRE) {
    u64 v = sorted[r];
    key = (u32)(v >> 32);
    u32 idx = 0xFFFFu - ((u32)v & 0xFFFFu);
    topbox[r] = props[idx];
    topkey[r] = key;
  }
  u64 inval = __ballot(key == 0u);
  if (threadIdx.x == 0) invalw[blockIdx.x] = inval;
}

// ---------------- 5) suppression bitmask: 94x94 tiles of 64x64 IoUs ----------------
__global__ void mask_k(const float4* __restrict__ topbox, u64* __restrict__ mask) {
  #pragma clang fp contract(off)
  __shared__ float4 cb[64];
  int jb = blockIdx.x;
  int i = blockIdx.y * 64 + threadIdx.x;
  int jj = jb * 64 + threadIdx.x;
  cb[threadIdx.x] = (jj < PRE) ? topbox[jj] : make_float4(0.f, 0.f, 0.f, 0.f);
  __syncthreads();
  if (i >= PRE) return;
  float4 b = topbox[i];
  float ai = (b.z - b.x + 1.0f) * (b.w - b.y + 1.0f);
  u64 bits = 0ULL;
  int jmax = min(64, PRE - jb * 64);
  for (int j = 0; j < jmax; ++j) {
    float4 c = cb[j];
    float aj = (c.z - c.x + 1.0f) * (c.w - c.y + 1.0f);
    float iw = fmaxf(fminf(b.z, c.z) - fmaxf(b.x, c.x) + 1.0f, 0.0f);
    float ih = fmaxf(fminf(b.w, c.w) - fmaxf(b.y, c.y) + 1.0f, 0.0f);
    float inter = iw * ih;
    float iou = inter / (ai + aj - inter);
    bits |= ((u64)(iou > 0.7f)) << j;
  }
  mask[(size_t)i * NWORDS + jb] = bits;
}

// ---------------- 6) sequential greedy scan: single wave ----------------
// Serial chain is pure SALU on the current 64-bit remv word `cur`; the
// distributed remv (lane l<47 holds words 2l,2l+1) is updated with
// predicated vector ORs OFF the chain. Word-w extracts via v_readlane
// (uniform lane index) are precomputed per 8-row chunk, also off-chain.
__device__ __forceinline__ u64 rl64(u64 v, int lane) {
  u32 lo = (u32)__builtin_amdgcn_readlane((int)(u32)v, lane);
  u32 hi = (u32)__builtin_amdgcn_readlane((int)(u32)(v >> 32), lane);
  return ((u64)hi << 32) | (u64)lo;
}

__global__ void nms_scan_k(const u64x2* __restrict__ maskv, const u64x2* __restrict__ invalv,
                           u64* __restrict__ keepw) {
  int lane = threadIdx.x;                       // 64 lanes; lanes 0..46 carry data
  u64 remvA = 0, remvB = 0;                     // words 2*lane, 2*lane+1
  if (lane < 47) { u64x2 v = invalv[lane]; remvA = v.x; remvB = v.y; }

  u64 LAb[3][8], LBb[3][8];
  u64 cur = 0, kw = 0;
  int kept = 0;

#define LOADC(cc, BUF) { \
    if ((cc) < 750) { \
      const u64x2* p = maskv + (size_t)(cc) * 8 * 47; \
      if (lane < 47) { \
        _Pragma("unroll") \
        for (int k = 0; k < 8; ++k) { \
          u64x2 v = p[(size_t)k * 47 + lane]; \
          LAb[BUF][k] = v.x; LBb[BUF][k] = v.y; \
        } \
      } \
    } }

#define PROCC(cc, BUF) { \
    const int w = (cc) >> 3; const int rlane = w >> 1; const int par = w & 1; \
    if (((cc) & 7) == 0) cur = par ? rl64(remvB, rlane) : rl64(remvA, rlane); \
    u64 sw[8]; \
    _Pragma("unroll") \
    for (int k = 0; k < 8; ++k) \
      sw[k] = par ? rl64(LBb[BUF][k], rlane) : rl64(LAb[BUF][k], rlane); \
    _Pragma("unroll") \
    for (int k = 0; k < 8; ++k) { \
      const int sh = ((cc) * 8 + k) & 63; \
      u64 keep = ((cur >> sh) & 1ULL) ^ 1ULL; \
      u64 km = 0ULL - keep;                 /* all-ones iff keep */ \
      cur   |= km & sw[k];                  /* the only serial dependency */ \
      remvA |= km & LAb[BUF][k]; \
      remvB |= km & LBb[BUF][k]; \
      kw    |= keep << sh; \
      kept  += (int)keep; \
    } \
    if (lane == 0) keepw[((cc) * 8 + 7) >> 6] = kw; \
    if (((cc) & 7) == 7) kw = 0ULL; \
    if (kept >= POST) return; }

  LOADC(0, 0); LOADC(1, 1); LOADC(2, 2);
  for (int base = 0; base < 750; base += 3) {
    PROCC(base + 0, 0); LOADC(base + 3, 0);
    PROCC(base + 1, 1); LOADC(base + 4, 1);
    PROCC(base + 2, 2); LOADC(base + 5, 2);
  }
#undef LOADC
#undef PROCC
}

// ---------------- 7) rank + scatter outputs ----------------
__global__ void scatter_k(const u64* __restrict__ keepw, const float4* __restrict__ topbox,
                          const u32* __restrict__ topkey, float* __restrict__ out) {
  __shared__ u64 wl[NWORDS];
  __shared__ u32 pre[NWORDS];
  int t = threadIdx.x;
  if (t < NWORDS) wl[t] = keepw[t];
  __syncthreads();
  if (t == 0) {
    u32 run = 0;
    for (int w = 0; w < NWORDS; ++w) { pre[w] = run; run += (u32)__popcll(wl[w]); }
  }
  __syncthreads();
  for (int i = t; i < PRE; i += 1024) {
    int w = i >> 6;
    u64 word = wl[w];
    if ((word >> (i & 63)) & 1ULL) {
      u32 rank = pre[w] + (u32)__popcll(word & ((1ULL << (i & 63)) - 1ULL));
      if (rank < POST) {
        float4 b = topbox[i];
        out[rank * 5 + 1] = b.x;
        out[rank * 5 + 2] = b.y;
        out[rank * 5 + 3] = b.z;
        out[rank * 5 + 4] = b.w;
        out[10000 + rank] = __uint_as_float(topkey[i] & 0x7FFFFFFFu);  // col 0 stays 0
      }
    }
  }
}

extern "C" void kernel_launch(void* const* d_in, const int* in_sizes, int n_in,
                              void* d_out, int out_size, void* d_ws, size_t ws_size,
                              hipStream_t stream) {
  const float* deltas = (const float*)d_in[0];
  const float* scores = (const float*)d_in[1];
  const int* imw = (const int*)d_in[2];
  const int* imh = (const int*)d_in[3];
  char* ws = (char*)d_ws;

  float4* props   = (float4*)(ws + OFF_PROPS);
  u64*    svals   = (u64*)(ws + OFF_SV);
  float4* topbox  = (float4*)(ws + OFF_TOPBOX);
  u64*    sorted  = (u64*)(ws + OFF_SORTED);
  u64*    sel     = (u64*)(ws + OFF_SEL);
  u32*    topkey  = (u32*)(ws + OFF_TOPKEY);
  u64*    invalw  = (u64*)(ws + OFF_INVALW);
  u64*    maskb   = (u64*)(ws + OFF_MASK);
  u32*    h1      = (u32*)(ws + OFF_H1);
  u32*    h2      = (u32*)(ws + OFF_H2);
  u32*    h3      = (u32*)(ws + OFF_H3);
  u32*    ctrl    = (u32*)(ws + OFF_CTRL);
  u64*    keepw   = (u64*)(ws + OFF_KEEPW);

  hipMemsetAsync(ws + OFF_ZERO, 0, ZERO_BYTES, stream);      // hists + ctrl + keepwords
  hipMemsetAsync(d_out, 0, 12000 * sizeof(float), stream);   // blob + scores zero-padded

  decode_k<<<144, 256, 0, stream>>>(deltas, scores, imw, imh, props, svals);

  hist_k<<<144, 256, 0, stream>>>(svals, h1, ctrl, 1);
  scan_k<<<1, 1024, 0, stream>>>(h1, ctrl, 1);
  hist_k<<<144, 256, 0, stream>>>(svals, h2, ctrl, 2);
  scan_k<<<1, 1024, 0, stream>>>(h2, ctrl, 2);
  hist_k<<<144, 256, 0, stream>>>(svals, h3, ctrl, 3);
  scan_k<<<1, 1024, 0, stream>>>(h3, ctrl, 3);

  compact_k<<<144, 256, 0, stream>>>(svals, ctrl, sel);
  sort_k<<<1, 1024, 0, stream>>>(sel, sorted);
  gather_k<<<94, 64, 0, stream>>>(sorted, props, topbox, topkey, invalw);

  dim3 mgrid(NWORDS, NWORDS);
  mask_k<<<mgrid, 64, 0, stream>>>(topbox, maskb);

  nms_scan_k<<<1, 64, 0, stream>>>((const u64x2*)maskb, (const u64x2*)invalw, keepw);
  scatter_k<<<1, 1024, 0, stream>>>(keepw, topbox, topkey, (float*)d_out);
}

// Round 3
// 510.081 us; speedup vs baseline: 1.5049x; 1.4637x over previous
//
#include <hip/hip_runtime.h>
#include <math.h>

typedef unsigned int u32;
typedef unsigned long long u64;

#define NANCH   36864
#define PRE     6000
#define POST    2000
#define NWORDS  94        // ceil(6000/64)

// ---------------- workspace layout (bytes) ----------------
#define OFF_PROPS   ((size_t)0)                    // 36864 * 16 = 589824
#define OFF_SV      ((size_t)589824)               // 36864 * 8  = 294912
#define OFF_TOPBOX  ((size_t)884736)               // 6016 * 16  = 96256
#define OFF_SORTED  ((size_t)980992)               // 6016 * 8   = 48128
#define OFF_SEL     ((size_t)1029120)              // 6016 * 8   = 48128
#define OFF_TOPKEY  ((size_t)1077248)              // 6016 * 4   = 24064
#define OFF_INVALW  ((size_t)1101312)              // 94 * 8 -> pad 768 (16B aligned)
#define OFF_MASK    ((size_t)1102080)              // 6000 * 94 * 8 = 4512000 (16B aligned)
#define OFF_ZERO    ((size_t)5614080)              // zeroed region start
#define OFF_H1      (OFF_ZERO)                     // 65536 * 4
#define OFF_H2      (OFF_H1 + 262144)
#define OFF_H3      (OFF_H2 + 262144)
#define OFF_CTRL    (OFF_H3 + 262144)              // 256 B: u32[0..7] + u64 T at +32
#define OFF_KEEPW   (OFF_CTRL + 256)               // 94*8 -> pad 768
#define ZERO_BYTES  ((size_t)(262144*3 + 256 + 768))

// base anchors for base_size=16, ratios(0.5,1,2), scales(8,16,32) — np.round (banker's) applied
__device__ __constant__ float BA[9][4] = {
  {-84.f,-40.f,99.f,55.f},   {-176.f,-88.f,191.f,103.f}, {-360.f,-184.f,375.f,199.f},
  {-56.f,-56.f,71.f,71.f},   {-120.f,-120.f,135.f,135.f},{-248.f,-248.f,263.f,263.f},
  {-36.f,-80.f,51.f,95.f},   {-80.f,-168.f,95.f,183.f},  {-168.f,-344.f,183.f,359.f}};

// ---------------- 1) decode ----------------
__global__ void decode_k(const float* __restrict__ deltas, const float* __restrict__ scores,
                         const int* __restrict__ imw_p, const int* __restrict__ imh_p,
                         float4* __restrict__ props, u64* __restrict__ sortvals) {
  #pragma clang fp contract(off)
  int i = blockIdx.x * 256 + threadIdx.x;
  if (i >= NANCH) return;
  int a = i % 9;
  int pix = i / 9;
  int x = pix & 63, y = pix >> 6;

  float sc = scores[(9 + a) * 4096 + pix];
  float d0 = deltas[(a * 4 + 0) * 4096 + pix];
  float d1 = deltas[(a * 4 + 1) * 4096 + pix];
  float d2 = deltas[(a * 4 + 2) * 4096 + pix];
  float d3 = deltas[(a * 4 + 3) * 4096 + pix];

  float gx = (float)(x * 16), gy = (float)(y * 16);
  float ax1 = gx + BA[a][0], ay1 = gy + BA[a][1];
  float ax2 = gx + BA[a][2], ay2 = gy + BA[a][3];
  float aw = ax2 - ax1 + 1.0f, ah = ay2 - ay1 + 1.0f;
  float acx = ax1 + 0.5f * aw, acy = ay1 + 0.5f * ah;

  float pcx = d0 * aw + acx;
  float pcy = d1 * ah + acy;
  float pw = (float)exp((double)d2) * aw;   // f64 exp -> correctly-rounded f32
  float ph = (float)exp((double)d3) * ah;

  float imw1 = (float)imw_p[0] - 1.0f, imh1 = (float)imh_p[0] - 1.0f;
  float x1 = fminf(fmaxf(pcx - 0.5f * pw, 0.0f), imw1);
  float y1 = fminf(fmaxf(pcy - 0.5f * ph, 0.0f), imh1);
  float x2 = fminf(fmaxf(pcx + 0.5f * pw, 0.0f), imw1);
  float y2 = fminf(fmaxf(pcy + 0.5f * ph, 0.0f), imh1);
  props[i] = make_float4(x1, y1, x2, y2);

  float thresh = 16.0f * ((float)imh_p[0] / (float)imw_p[0]);
  bool keep = (x2 - x1 + 1.0f >= thresh) && (y2 - y1 + 1.0f >= thresh);
  u32 key = keep ? (__float_as_uint(sc) | 0x80000000u) : 0u;  // scores >= 0
  sortvals[i] = ((u64)key << 32) | (u64)(0xFFFFFFFFu - (u32)i); // distinct; desc order == top_k order
}

// ---------------- 2) exact top-6000 threshold via 3-level radix histogram ----------------
__global__ void hist_k(const u64* __restrict__ sv, u32* __restrict__ hist,
                       const u32* __restrict__ ctrl, int level) {
  int i = blockIdx.x * 256 + threadIdx.x;
  if (i >= NANCH) return;
  u64 v = sv[i];
  if (level == 1) {
    atomicAdd(&hist[(u32)(v >> 48)], 1u);
  } else if (level == 2) {
    if ((u32)(v >> 48) == ctrl[0]) atomicAdd(&hist[(u32)(v >> 32) & 0xFFFFu], 1u);
  } else {
    u32 pfx = (ctrl[0] << 16) | ctrl[2];
    if ((u32)(v >> 32) == pfx) atomicAdd(&hist[(u32)v & 0xFFFFu], 1u);
  }
}

__global__ void scan_k(const u32* __restrict__ hist, u32* __restrict__ ctrl, int level) {
  __shared__ u32 part[1024];
  int t = threadIdx.x;
  u32 ssum = 0;
  for (int b = 0; b < 64; ++b) ssum += hist[t * 64 + b];
  part[t] = ssum;
  __syncthreads();
  if (t == 0) {
    u32 Rin = (level == 1) ? (u32)PRE : ctrl[(level - 1) * 2 - 1];
    u32 acc = 0; int pt;
    for (pt = 1023; pt >= 0; --pt) {
      if (acc + part[pt] >= Rin) break;
      acc += part[pt];
    }
    int chosen = pt * 64; u32 Rout = Rin;
    for (int b = pt * 64 + 63; b >= pt * 64; --b) {
      u32 h = hist[b];
      if (acc + h >= Rin) { chosen = b; Rout = Rin - acc; break; }
      acc += h;
    }
    ctrl[(level - 1) * 2] = (u32)chosen;
    ctrl[(level - 1) * 2 + 1] = Rout;
    if (level == 3) {
      // bits 16..31 of every sortval are 0xFFFF (idx < 65536)
      u64 T = ((u64)ctrl[0] << 48) | ((u64)ctrl[2] << 32) | 0xFFFF0000ULL | (u64)(u32)chosen;
      *(u64*)(&ctrl[8]) = T;   // exactly 6000 sortvals are >= T (all distinct)
    }
  }
}

__global__ void compact_k(const u64* __restrict__ sv, u32* __restrict__ ctrl,
                          u64* __restrict__ sel) {
  int i = blockIdx.x * 256 + threadIdx.x;
  if (i >= NANCH) return;
  u64 T = *(const u64*)(&ctrl[8]);
  u64 v = sv[i];
  if (v >= T) {
    u32 p = atomicAdd(&ctrl[6], 1u);
    sel[p] = v;
  }
}

// ---------------- 3) single-block bitonic sort of the 6000 selected (desc) ----------------
__global__ void sort_k(const u64* __restrict__ sel, u64* __restrict__ sorted) {
  __shared__ u64 s[8192];   // 64 KiB
  int tid = threadIdx.x;
  for (int idx = tid; idx < 8192; idx += 1024)
    s[idx] = (idx < PRE) ? ~sel[idx] : ~0ULL;   // ascending sort of complement == descending original
  __syncthreads();
  for (int k = 2; k <= 8192; k <<= 1) {
    for (int j = k >> 1; j > 0; j >>= 1) {
      for (int t = tid; t < 8192; t += 1024) {
        int ixj = t ^ j;
        if (ixj > t) {
          u64 A = s[t], B = s[ixj];
          bool asc = ((t & k) == 0);
          if (asc ? (A > B) : (A < B)) { s[t] = B; s[ixj] = A; }
        }
      }
      __syncthreads();
    }
  }
  for (int idx = tid; idx < PRE; idx += 1024) sorted[idx] = ~s[idx];
}

// ---------------- 4) gather boxes/keys; build invalid-bit words ----------------
__global__ void gather_k(const u64* __restrict__ sorted, const float4* __restrict__ props,
                         float4* __restrict__ topbox, u32* __restrict__ topkey,
                         u64* __restrict__ invalw) {
  int r = blockIdx.x * 64 + threadIdx.x;
  u32 key = 0;
  if (r < PRE) {
    u64 v = sorted[r];
    key = (u32)(v >> 32);
    u32 idx = 0xFFFFu - ((u32)v & 0xFFFFu);
    topbox[r] = props[idx];
    topkey[r] = key;
  }
  u64 inval = __ballot(key == 0u);
  if (threadIdx.x == 0) invalw[blockIdx.x] = inval;
}

// ---------------- 5) suppression bitmask: upper-triangle 64x64 tiles ----------------
__global__ void mask_k(const float4* __restrict__ topbox, u64* __restrict__ mask) {
  #pragma clang fp contract(off)
  __shared__ float4 cb[64];
  int jb = blockIdx.x;
  if (jb < (int)blockIdx.y) return;   // only w >= row-block is ever read
  int i = blockIdx.y * 64 + threadIdx.x;
  int jj = jb * 64 + threadIdx.x;
  cb[threadIdx.x] = (jj < PRE) ? topbox[jj] : make_float4(0.f, 0.f, 0.f, 0.f);
  __syncthreads();
  if (i >= PRE) return;
  float4 b = topbox[i];
  float ai = (b.z - b.x + 1.0f) * (b.w - b.y + 1.0f);
  u64 bits = 0ULL;
  int jmax = min(64, PRE - jb * 64);
  for (int j = 0; j < jmax; ++j) {
    float4 c = cb[j];
    float aj = (c.z - c.x + 1.0f) * (c.w - c.y + 1.0f);
    float iw = fmaxf(fminf(b.z, c.z) - fmaxf(b.x, c.x) + 1.0f, 0.0f);
    float ih = fmaxf(fminf(b.w, c.w) - fmaxf(b.y, c.y) + 1.0f, 0.0f);
    float inter = iw * ih;
    float iou = inter / (ai + aj - inter);
    bits |= ((u64)(iou > 0.7f)) << j;
  }
  mask[(size_t)i * NWORDS + jb] = bits;
}

// ---------------- 6) block-parallel greedy scan ----------------
// 1024 threads, 16 waves, one workgroup. Thread (g = t>>7, w = t&127, w<94)
// streams mask[64b+g*8+j][w] (j=0..7) per step b, triple-buffered, prefetch
// depth 2. It accumulates its group-partial remv word `rv` with predicated
// ORs (off the serial chain). The 8 partials for word b are published into
// LDS via atomicOr exactly once, at step b. Wave 0 runs the per-word greedy
// chain in SALU, iterating only over kept rows via ctz.
__device__ __forceinline__ u64 rl64(u64 v, int lane) {
  u32 lo = (u32)__builtin_amdgcn_readlane((int)(u32)v, lane);
  u32 hi = (u32)__builtin_amdgcn_readlane((int)(u32)(v >> 32), lane);
  return ((u64)hi << 32) | (u64)lo;
}
__device__ __forceinline__ u64 rfl64(u64 v) {
  u32 lo = (u32)__builtin_amdgcn_readfirstlane((int)(u32)v);
  u32 hi = (u32)__builtin_amdgcn_readfirstlane((int)(u32)(v >> 32));
  return ((u64)hi << 32) | (u64)lo;
}

__global__ void __launch_bounds__(1024) nms_scan_k(const u64* __restrict__ mask,
                                                   const u64* __restrict__ invalw,
                                                   u64* __restrict__ keepw) {
  __shared__ u64 Lrem[NWORDS];
  __shared__ u64 Ldiag[64];
  __shared__ u64 Lkeep;
  __shared__ int Lstop;
  const int t = threadIdx.x;
  const int g = t >> 7;                 // 8 groups of 128 threads
  const int w = t & 127;                // word owned (if < 94)
  const bool loader = (w < NWORDS);
  if (t < NWORDS) Lrem[t] = invalw[t];
  if (t == 0) Lstop = 0;
  u64 rv = 0;                           // group-partial remv for word w
  u64 B0[8], B1[8], B2[8];
  int kept = 0;

#define ISSUE(bb, BUF) \
  if ((bb) < NWORDS && loader) { \
    const int row0_ = (bb) * 64 + g * 8; \
    const u64* pp_ = mask + (size_t)row0_ * NWORDS + w; \
    _Pragma("unroll") \
    for (int j = 0; j < 8; ++j) { \
      bool ok_ = (w >= (bb)) && (row0_ + j < PRE); \
      BUF[j] = ok_ ? pp_[(size_t)j * NWORDS] : 0ULL; \
    } \
  }

#define STEP(bb, BUF, BUF2) { \
    if (w == (bb)) {                     /* 8 publishers (one per group) */ \
      atomicOr((u32*)&Lrem[(bb)], (u32)rv); \
      atomicOr(((u32*)&Lrem[(bb)]) + 1, (u32)(rv >> 32)); \
      _Pragma("unroll") \
      for (int j = 0; j < 8; ++j) Ldiag[g * 8 + j] = BUF[j]; \
    } \
    __syncthreads();                     /* X: diag + Lrem[b] visible */ \
    ISSUE((bb) + 2, BUF2)                /* overlaps wave-0 chain */ \
    if (t < 64) { \
      u64 dgl = Ldiag[t]; \
      u64 avail = ~rfl64(Lrem[(bb)]);    /* keepable rows in this word */ \
      u64 kb = 0; \
      while (avail) { \
        int i_ = __builtin_ctzll(avail); \
        kb |= 1ULL << i_; \
        u64 di_ = rl64(dgl, i_); \
        avail &= ~di_ & ~((2ULL << i_) - 1ULL); /* 2<<63 wraps to 0 -> ~(-1)=0 */ \
      } \
      if (t == 0) { \
        keepw[(bb)] = kb; \
        Lkeep = kb; \
        kept += (int)__popcll(kb); \
        if (kept >= POST) Lstop = 1; \
      } \
    } \
    __syncthreads();                     /* Y: kb + stop visible */ \
    { \
      u64 kb_ = Lkeep; \
      const int base_ = g * 8; \
      _Pragma("unroll") \
      for (int j = 0; j < 8; ++j) { \
        u64 k_ = (kb_ >> (base_ + j)) & 1ULL; \
        rv |= (0ULL - k_) & BUF[j]; \
      } \
    } \
    if (Lstop) break; }

  ISSUE(0, B0)
  ISSUE(1, B1)
  for (int bb = 0; bb < NWORDS; bb += 3) {
    STEP(bb, B0, B2)
    if (bb + 1 < NWORDS) STEP(bb + 1, B1, B0)
    if (bb + 2 < NWORDS) STEP(bb + 2, B2, B1)
  }
#undef ISSUE
#undef STEP
}

// ---------------- 7) rank + scatter outputs ----------------
__global__ void scatter_k(const u64* __restrict__ keepw, const float4* __restrict__ topbox,
                          const u32* __restrict__ topkey, float* __restrict__ out) {
  __shared__ u64 wl[NWORDS];
  __shared__ u32 pre[NWORDS];
  int t = threadIdx.x;
  if (t < NWORDS) wl[t] = keepw[t];
  __syncthreads();
  if (t == 0) {
    u32 run = 0;
    for (int w = 0; w < NWORDS; ++w) { pre[w] = run; run += (u32)__popcll(wl[w]); }
  }
  __syncthreads();
  for (int i = t; i < PRE; i += 1024) {
    int w = i >> 6;
    u64 word = wl[w];
    if ((word >> (i & 63)) & 1ULL) {
      u32 rank = pre[w] + (u32)__popcll(word & ((1ULL << (i & 63)) - 1ULL));
      if (rank < POST) {
        float4 b = topbox[i];
        out[rank * 5 + 1] = b.x;
        out[rank * 5 + 2] = b.y;
        out[rank * 5 + 3] = b.z;
        out[rank * 5 + 4] = b.w;
        out[10000 + rank] = __uint_as_float(topkey[i] & 0x7FFFFFFFu);  // col 0 stays 0
      }
    }
  }
}

extern "C" void kernel_launch(void* const* d_in, const int* in_sizes, int n_in,
                              void* d_out, int out_size, void* d_ws, size_t ws_size,
                              hipStream_t stream) {
  const float* deltas = (const float*)d_in[0];
  const float* scores = (const float*)d_in[1];
  const int* imw = (const int*)d_in[2];
  const int* imh = (const int*)d_in[3];
  char* ws = (char*)d_ws;

  float4* props   = (float4*)(ws + OFF_PROPS);
  u64*    svals   = (u64*)(ws + OFF_SV);
  float4* topbox  = (float4*)(ws + OFF_TOPBOX);
  u64*    sorted  = (u64*)(ws + OFF_SORTED);
  u64*    sel     = (u64*)(ws + OFF_SEL);
  u32*    topkey  = (u32*)(ws + OFF_TOPKEY);
  u64*    invalw  = (u64*)(ws + OFF_INVALW);
  u64*    maskb   = (u64*)(ws + OFF_MASK);
  u32*    h1      = (u32*)(ws + OFF_H1);
  u32*    h2      = (u32*)(ws + OFF_H2);
  u32*    h3      = (u32*)(ws + OFF_H3);
  u32*    ctrl    = (u32*)(ws + OFF_CTRL);
  u64*    keepw   = (u64*)(ws + OFF_KEEPW);

  hipMemsetAsync(ws + OFF_ZERO, 0, ZERO_BYTES, stream);      // hists + ctrl + keepwords
  hipMemsetAsync(d_out, 0, 12000 * sizeof(float), stream);   // blob + scores zero-padded

  decode_k<<<144, 256, 0, stream>>>(deltas, scores, imw, imh, props, svals);

  hist_k<<<144, 256, 0, stream>>>(svals, h1, ctrl, 1);
  scan_k<<<1, 1024, 0, stream>>>(h1, ctrl, 1);
  hist_k<<<144, 256, 0, stream>>>(svals, h2, ctrl, 2);
  scan_k<<<1, 1024, 0, stream>>>(h2, ctrl, 2);
  hist_k<<<144, 256, 0, stream>>>(svals, h3, ctrl, 3);
  scan_k<<<1, 1024, 0, stream>>>(h3, ctrl, 3);

  compact_k<<<144, 256, 0, stream>>>(svals, ctrl, sel);
  sort_k<<<1, 1024, 0, stream>>>(sel, sorted);
  gather_k<<<94, 64, 0, stream>>>(sorted, props, topbox, topkey, invalw);

  dim3 mgrid(NWORDS, NWORDS);
  mask_k<<<mgrid, 64, 0, stream>>>(topbox, maskb);

  nms_scan_k<<<1, 1024, 0, stream>>>(maskb, invalw, keepw);
  scatter_k<<<1, 1024, 0, stream>>>(keepw, topbox, topkey, (float*)d_out);
}

// Round 4
// 408.804 us; speedup vs baseline: 1.8778x; 1.2477x over previous
//
#include <hip/hip_runtime.h>
#include <math.h>

typedef unsigned int u32;
typedef unsigned long long u64;

#define NANCH   36864
#define PRE     6000
#define POST    2000
#define NWORDS  94        // ceil(6000/64)

// ---------------- workspace layout (bytes) ----------------
#define OFF_PROPS   ((size_t)0)                    // 36864 * 16 = 589824
#define OFF_SV      ((size_t)589824)               // 36864 * 8  = 294912
#define OFF_TOPBOX  ((size_t)884736)               // 6016 * 16  = 96256
#define OFF_SORTED  ((size_t)980992)               // 6016 * 8   = 48128
#define OFF_SEL     ((size_t)1029120)              // 6016 * 8   = 48128
#define OFF_TOPKEY  ((size_t)1077248)              // 6016 * 4   = 24064
#define OFF_INVALW  ((size_t)1101312)              // 94 * 8 -> pad 768 (16B aligned)
#define OFF_MASK    ((size_t)1102080)              // 6000 * 94 * 8 = 4512000 (16B aligned)
#define OFF_ZERO    ((size_t)5614080)              // zeroed region start
#define OFF_H1      (OFF_ZERO)                     // 65536 * 4
#define OFF_H2      (OFF_H1 + 262144)
#define OFF_H3      (OFF_H2 + 262144)
#define OFF_CTRL    (OFF_H3 + 262144)              // 256 B: u32[0..7] + u64 T at +32
#define OFF_KEEPW   (OFF_CTRL + 256)               // 94*8 -> pad 768
#define OFF_RANK    (OFF_KEEPW + 768)              // 6016 * 4 = 24064
#define ZERO_BYTES  ((size_t)(262144*3 + 256 + 768 + 24064))

// base anchors for base_size=16, ratios(0.5,1,2), scales(8,16,32) — np.round (banker's) applied
__device__ __constant__ float BA[9][4] = {
  {-84.f,-40.f,99.f,55.f},   {-176.f,-88.f,191.f,103.f}, {-360.f,-184.f,375.f,199.f},
  {-56.f,-56.f,71.f,71.f},   {-120.f,-120.f,135.f,135.f},{-248.f,-248.f,263.f,263.f},
  {-36.f,-80.f,51.f,95.f},   {-80.f,-168.f,95.f,183.f},  {-168.f,-344.f,183.f,359.f}};

// ---------------- 1) decode ----------------
__global__ void decode_k(const float* __restrict__ deltas, const float* __restrict__ scores,
                         const int* __restrict__ imw_p, const int* __restrict__ imh_p,
                         float4* __restrict__ props, u64* __restrict__ sortvals) {
  #pragma clang fp contract(off)
  int i = blockIdx.x * 256 + threadIdx.x;
  if (i >= NANCH) return;
  int a = i % 9;
  int pix = i / 9;
  int x = pix & 63, y = pix >> 6;

  float sc = scores[(9 + a) * 4096 + pix];
  float d0 = deltas[(a * 4 + 0) * 4096 + pix];
  float d1 = deltas[(a * 4 + 1) * 4096 + pix];
  float d2 = deltas[(a * 4 + 2) * 4096 + pix];
  float d3 = deltas[(a * 4 + 3) * 4096 + pix];

  float gx = (float)(x * 16), gy = (float)(y * 16);
  float ax1 = gx + BA[a][0], ay1 = gy + BA[a][1];
  float ax2 = gx + BA[a][2], ay2 = gy + BA[a][3];
  float aw = ax2 - ax1 + 1.0f, ah = ay2 - ay1 + 1.0f;
  float acx = ax1 + 0.5f * aw, acy = ay1 + 0.5f * ah;

  float pcx = d0 * aw + acx;
  float pcy = d1 * ah + acy;
  float pw = (float)exp((double)d2) * aw;   // f64 exp -> correctly-rounded f32
  float ph = (float)exp((double)d3) * ah;

  float imw1 = (float)imw_p[0] - 1.0f, imh1 = (float)imh_p[0] - 1.0f;
  float x1 = fminf(fmaxf(pcx - 0.5f * pw, 0.0f), imw1);
  float y1 = fminf(fmaxf(pcy - 0.5f * ph, 0.0f), imh1);
  float x2 = fminf(fmaxf(pcx + 0.5f * pw, 0.0f), imw1);
  float y2 = fminf(fmaxf(pcy + 0.5f * ph, 0.0f), imh1);
  props[i] = make_float4(x1, y1, x2, y2);

  float thresh = 16.0f * ((float)imh_p[0] / (float)imw_p[0]);
  bool keep = (x2 - x1 + 1.0f >= thresh) && (y2 - y1 + 1.0f >= thresh);
  u32 key = keep ? (__float_as_uint(sc) | 0x80000000u) : 0u;  // scores >= 0
  sortvals[i] = ((u64)key << 32) | (u64)(0xFFFFFFFFu - (u32)i); // distinct; desc order == top_k order
}

// ---------------- 2) exact top-6000 threshold via 3-level radix histogram ----------------
__global__ void hist_k(const u64* __restrict__ sv, u32* __restrict__ hist,
                       const u32* __restrict__ ctrl, int level) {
  int i = blockIdx.x * 256 + threadIdx.x;
  if (i >= NANCH) return;
  u64 v = sv[i];
  if (level == 1) {
    atomicAdd(&hist[(u32)(v >> 48)], 1u);
  } else if (level == 2) {
    if ((u32)(v >> 48) == ctrl[0]) atomicAdd(&hist[(u32)(v >> 32) & 0xFFFFu], 1u);
  } else {
    u32 pfx = (ctrl[0] << 16) | ctrl[2];
    if ((u32)(v >> 32) == pfx) atomicAdd(&hist[(u32)v & 0xFFFFu], 1u);
  }
}

__global__ void scan_k(const u32* __restrict__ hist, u32* __restrict__ ctrl, int level) {
  __shared__ u32 part[1024];
  int t = threadIdx.x;
  u32 ssum = 0;
  for (int b = 0; b < 64; ++b) ssum += hist[t * 64 + b];
  part[t] = ssum;
  __syncthreads();
  if (t == 0) {
    u32 Rin = (level == 1) ? (u32)PRE : ctrl[(level - 1) * 2 - 1];
    u32 acc = 0; int pt;
    for (pt = 1023; pt >= 0; --pt) {
      if (acc + part[pt] >= Rin) break;
      acc += part[pt];
    }
    int chosen = pt * 64; u32 Rout = Rin;
    for (int b = pt * 64 + 63; b >= pt * 64; --b) {
      u32 h = hist[b];
      if (acc + h >= Rin) { chosen = b; Rout = Rin - acc; break; }
      acc += h;
    }
    ctrl[(level - 1) * 2] = (u32)chosen;
    ctrl[(level - 1) * 2 + 1] = Rout;
    if (level == 3) {
      // bits 16..31 of every sortval are 0xFFFF (idx < 65536)
      u64 T = ((u64)ctrl[0] << 48) | ((u64)ctrl[2] << 32) | 0xFFFF0000ULL | (u64)(u32)chosen;
      *(u64*)(&ctrl[8]) = T;   // exactly 6000 sortvals are >= T (all distinct)
    }
  }
}

__global__ void compact_k(const u64* __restrict__ sv, u32* __restrict__ ctrl,
                          u64* __restrict__ sel) {
  int i = blockIdx.x * 256 + threadIdx.x;
  if (i >= NANCH) return;
  u64 T = *(const u64*)(&ctrl[8]);
  u64 v = sv[i];
  if (v >= T) {
    u32 p = atomicAdd(&ctrl[6], 1u);
    sel[p] = v;
  }
}

// ---------------- 3) sort via all-pairs rank (keys are all distinct) ----------------
// rank[i] = #{j : sel[j] > sel[i]}  ->  sorted[rank[i]] = sel[i] is exact
// descending sort. Grid (24 i-blocks x 4 j-chunks), j-chunk staged via LDS.
#define JCHUNK 1500
__global__ void rank_k(const u64* __restrict__ sel, u32* __restrict__ rank) {
  __shared__ u64 sj[256];
  int i = blockIdx.x * 256 + threadIdx.x;
  u64 vi = (i < PRE) ? sel[i] : 0ULL;
  int j0 = blockIdx.y * JCHUNK;
  int j1 = min(j0 + JCHUNK, PRE);
  u32 cnt = 0;
  for (int jb = j0; jb < j1; jb += 256) {
    int nj = min(256, j1 - jb);
    __syncthreads();
    if (threadIdx.x < nj) sj[threadIdx.x] = sel[jb + threadIdx.x];
    __syncthreads();
    #pragma unroll 8
    for (int j = 0; j < nj; ++j) cnt += (u32)(sj[j] > vi);
  }
  if (i < PRE && cnt) atomicAdd(&rank[i], cnt);
}

__global__ void rankscatter_k(const u64* __restrict__ sel, const u32* __restrict__ rank,
                              u64* __restrict__ sorted) {
  int i = blockIdx.x * 256 + threadIdx.x;
  if (i < PRE) sorted[rank[i]] = sel[i];
}

// ---------------- 4) gather boxes/keys; build invalid-bit words ----------------
__global__ void gather_k(const u64* __restrict__ sorted, const float4* __restrict__ props,
                         float4* __restrict__ topbox, u32* __restrict__ topkey,
                         u64* __restrict__ invalw) {
  int r = blockIdx.x * 64 + threadIdx.x;
  u32 key = 0;
  if (r < PRE) {
    u64 v = sorted[r];
    key = (u32)(v >> 32);
    u32 idx = 0xFFFFu - ((u32)v & 0xFFFFu);
    topbox[r] = props[idx];
    topkey[r] = key;
  }
  u64 inval = __ballot(key == 0u);
  if (threadIdx.x == 0) invalw[blockIdx.x] = inval;
}

// ---------------- 5) suppression bitmask: upper-triangle 64x64 tiles ----------------
__global__ void mask_k(const float4* __restrict__ topbox, u64* __restrict__ mask) {
  #pragma clang fp contract(off)
  __shared__ float4 cb[64];
  int jb = blockIdx.x;
  if (jb < (int)blockIdx.y) return;   // only w >= row-block is ever read
  int i = blockIdx.y * 64 + threadIdx.x;
  int jj = jb * 64 + threadIdx.x;
  cb[threadIdx.x] = (jj < PRE) ? topbox[jj] : make_float4(0.f, 0.f, 0.f, 0.f);
  __syncthreads();
  if (i >= PRE) return;
  float4 b = topbox[i];
  float ai = (b.z - b.x + 1.0f) * (b.w - b.y + 1.0f);
  u64 bits = 0ULL;
  int jmax = min(64, PRE - jb * 64);
  for (int j = 0; j < jmax; ++j) {
    float4 c = cb[j];
    float aj = (c.z - c.x + 1.0f) * (c.w - c.y + 1.0f);
    float iw = fmaxf(fminf(b.z, c.z) - fmaxf(b.x, c.x) + 1.0f, 0.0f);
    float ih = fmaxf(fminf(b.w, c.w) - fmaxf(b.y, c.y) + 1.0f, 0.0f);
    float inter = iw * ih;
    float iou = inter / (ai + aj - inter);
    bits |= ((u64)(iou > 0.7f)) << j;
  }
  mask[(size_t)i * NWORDS + jb] = bits;
}

// ---------------- 6) block-parallel greedy scan ----------------
// 1024 threads, 16 waves, one workgroup. Thread (g = t>>7, w = t&127, w<94)
// streams mask[64b+g*8+j][w] (j=0..7) per step b, triple-buffered, prefetch
// depth 2. It accumulates its group-partial remv word `rv` with predicated
// ORs (off the serial chain). The 8 partials for word b are published into
// LDS via atomicOr exactly once, at step b. Wave 0 runs the per-word greedy
// chain in SALU, iterating only over kept rows via ctz.
__device__ __forceinline__ u64 rl64(u64 v, int lane) {
  u32 lo = (u32)__builtin_amdgcn_readlane((int)(u32)v, lane);
  u32 hi = (u32)__builtin_amdgcn_readlane((int)(u32)(v >> 32), lane);
  return ((u64)hi << 32) | (u64)lo;
}
__device__ __forceinline__ u64 rfl64(u64 v) {
  u32 lo = (u32)__builtin_amdgcn_readfirstlane((int)(u32)v);
  u32 hi = (u32)__builtin_amdgcn_readfirstlane((int)(u32)(v >> 32));
  return ((u64)hi << 32) | (u64)lo;
}

__global__ void __launch_bounds__(1024) nms_scan_k(const u64* __restrict__ mask,
                                                   const u64* __restrict__ invalw,
                                                   u64* __restrict__ keepw) {
  __shared__ u64 Lrem[NWORDS];
  __shared__ u64 Ldiag[64];
  __shared__ u64 Lkeep;
  __shared__ int Lstop;
  const int t = threadIdx.x;
  const int g = t >> 7;                 // 8 groups of 128 threads
  const int w = t & 127;                // word owned (if < 94)
  const bool loader = (w < NWORDS);
  if (t < NWORDS) Lrem[t] = invalw[t];
  if (t == 0) Lstop = 0;
  u64 rv = 0;                           // group-partial remv for word w
  u64 B0[8], B1[8], B2[8];
  int kept = 0;

#define ISSUE(bb, BUF) \
  if ((bb) < NWORDS && loader) { \
    const int row0_ = (bb) * 64 + g * 8; \
    const u64* pp_ = mask + (size_t)row0_ * NWORDS + w; \
    _Pragma("unroll") \
    for (int j = 0; j < 8; ++j) { \
      bool ok_ = (w >= (bb)) && (row0_ + j < PRE); \
      BUF[j] = ok_ ? pp_[(size_t)j * NWORDS] : 0ULL; \
    } \
  }

#define STEP(bb, BUF, BUF2) { \
    if (w == (bb)) {                     /* 8 publishers (one per group) */ \
      atomicOr((u32*)&Lrem[(bb)], (u32)rv); \
      atomicOr(((u32*)&Lrem[(bb)]) + 1, (u32)(rv >> 32)); \
      _Pragma("unroll") \
      for (int j = 0; j < 8; ++j) Ldiag[g * 8 + j] = BUF[j]; \
    } \
    __syncthreads();                     /* X: diag + Lrem[b] visible */ \
    ISSUE((bb) + 2, BUF2)                /* overlaps wave-0 chain */ \
    if (t < 64) { \
      u64 dgl = Ldiag[t]; \
      u64 avail = ~rfl64(Lrem[(bb)]);    /* keepable rows in this word */ \
      u64 kb = 0; \
      while (avail) { \
        int i_ = __builtin_ctzll(avail); \
        kb |= 1ULL << i_; \
        u64 di_ = rl64(dgl, i_); \
        avail &= ~di_ & ~((2ULL << i_) - 1ULL); /* 2<<63 wraps to 0 -> ~(-1)=0 */ \
      } \
      if (t == 0) { \
        keepw[(bb)] = kb; \
        Lkeep = kb; \
        kept += (int)__popcll(kb); \
        if (kept >= POST) Lstop = 1; \
      } \
    } \
    __syncthreads();                     /* Y: kb + stop visible */ \
    { \
      u64 kb_ = Lkeep; \
      const int base_ = g * 8; \
      _Pragma("unroll") \
      for (int j = 0; j < 8; ++j) { \
        u64 k_ = (kb_ >> (base_ + j)) & 1ULL; \
        rv |= (0ULL - k_) & BUF[j]; \
      } \
    } \
    if (Lstop) break; }

  ISSUE(0, B0)
  ISSUE(1, B1)
  for (int bb = 0; bb < NWORDS; bb += 3) {
    STEP(bb, B0, B2)
    if (bb + 1 < NWORDS) STEP(bb + 1, B1, B0)
    if (bb + 2 < NWORDS) STEP(bb + 2, B2, B1)
  }
#undef ISSUE
#undef STEP
}

// ---------------- 7) rank + scatter outputs ----------------
__global__ void scatter_k(const u64* __restrict__ keepw, const float4* __restrict__ topbox,
                          const u32* __restrict__ topkey, float* __restrict__ out) {
  __shared__ u64 wl[NWORDS];
  __shared__ u32 pre[NWORDS];
  int t = threadIdx.x;
  if (t < NWORDS) wl[t] = keepw[t];
  __syncthreads();
  if (t == 0) {
    u32 run = 0;
    for (int w = 0; w < NWORDS; ++w) { pre[w] = run; run += (u32)__popcll(wl[w]); }
  }
  __syncthreads();
  for (int i = t; i < PRE; i += 1024) {
    int w = i >> 6;
    u64 word = wl[w];
    if ((word >> (i & 63)) & 1ULL) {
      u32 rank = pre[w] + (u32)__popcll(word & ((1ULL << (i & 63)) - 1ULL));
      if (rank < POST) {
        float4 b = topbox[i];
        out[rank * 5 + 1] = b.x;
        out[rank * 5 + 2] = b.y;
        out[rank * 5 + 3] = b.z;
        out[rank * 5 + 4] = b.w;
        out[10000 + rank] = __uint_as_float(topkey[i] & 0x7FFFFFFFu);  // col 0 stays 0
      }
    }
  }
}

extern "C" void kernel_launch(void* const* d_in, const int* in_sizes, int n_in,
                              void* d_out, int out_size, void* d_ws, size_t ws_size,
                              hipStream_t stream) {
  const float* deltas = (const float*)d_in[0];
  const float* scores = (const float*)d_in[1];
  const int* imw = (const int*)d_in[2];
  const int* imh = (const int*)d_in[3];
  char* ws = (char*)d_ws;

  float4* props   = (float4*)(ws + OFF_PROPS);
  u64*    svals   = (u64*)(ws + OFF_SV);
  float4* topbox  = (float4*)(ws + OFF_TOPBOX);
  u64*    sorted  = (u64*)(ws + OFF_SORTED);
  u64*    sel     = (u64*)(ws + OFF_SEL);
  u32*    topkey  = (u32*)(ws + OFF_TOPKEY);
  u64*    invalw  = (u64*)(ws + OFF_INVALW);
  u64*    maskb   = (u64*)(ws + OFF_MASK);
  u32*    h1      = (u32*)(ws + OFF_H1);
  u32*    h2      = (u32*)(ws + OFF_H2);
  u32*    h3      = (u32*)(ws + OFF_H3);
  u32*    ctrl    = (u32*)(ws + OFF_CTRL);
  u64*    keepw   = (u64*)(ws + OFF_KEEPW);
  u32*    rankb   = (u32*)(ws + OFF_RANK);

  hipMemsetAsync(ws + OFF_ZERO, 0, ZERO_BYTES, stream);      // hists + ctrl + keepwords + rank
  hipMemsetAsync(d_out, 0, 12000 * sizeof(float), stream);   // blob + scores zero-padded

  decode_k<<<144, 256, 0, stream>>>(deltas, scores, imw, imh, props, svals);

  hist_k<<<144, 256, 0, stream>>>(svals, h1, ctrl, 1);
  scan_k<<<1, 1024, 0, stream>>>(h1, ctrl, 1);
  hist_k<<<144, 256, 0, stream>>>(svals, h2, ctrl, 2);
  scan_k<<<1, 1024, 0, stream>>>(h2, ctrl, 2);
  hist_k<<<144, 256, 0, stream>>>(svals, h3, ctrl, 3);
  scan_k<<<1, 1024, 0, stream>>>(h3, ctrl, 3);

  compact_k<<<144, 256, 0, stream>>>(svals, ctrl, sel);

  dim3 rgrid(24, 4);
  rank_k<<<rgrid, 256, 0, stream>>>(sel, rankb);
  rankscatter_k<<<24, 256, 0, stream>>>(sel, rankb, sorted);

  gather_k<<<94, 64, 0, stream>>>(sorted, props, topbox, topkey, invalw);

  dim3 mgrid(NWORDS, NWORDS);
  mask_k<<<mgrid, 64, 0, stream>>>(topbox, maskb);

  nms_scan_k<<<1, 1024, 0, stream>>>(maskb, invalw, keepw);
  scatter_k<<<1, 1024, 0, stream>>>(keepw, topbox, topkey, (float*)d_out);
}